// Round 12
// baseline (37.499 us; speedup 1.0000x reference)
//
#include <hip/hip_runtime.h>
#include <hip/hip_fp16.h>

// Correlation layer, specialized: s1=2, s2=1, d=4 -> integer even sampling,
// bilinear weights exactly 0 -> pure gather:
// out[b, j*9+i, h1, w1] = (1/256) * sum_c x1[b,c,2h1,2w1] * x2[b,c,2(h1+j-4),2(w1+i-4)]
//
// Dense-GEMM reformulation: per batch, Gram[p,q] = sum_c A[c,p]*B[c,q] with
// p,q over the 24x24 downsampled grid (576). Only band tile-pairs computed.
// Chain: pack (fp32 -> K-major bf16) -> banded 64x64 MFMA GEMM (fp16 Gram)
// -> gather (band extraction + boundary zeros + 1/256 scale).

typedef __attribute__((ext_vector_type(8))) short short8;
typedef __attribute__((ext_vector_type(4))) float f32x4;

constexpr int NB = 16, NC = 256, NH = 48, NW = 48;
constexpr int H1 = 24, W1 = 24, NK = 81, HW = NH * NW;
constexpr int NP = 576;                    // downsampled positions per batch
constexpr int OUTSZ = NB * NK * H1 * W1;   // 746496
constexpr size_t APK_HALFS = (size_t)NB * NP * NC;       // 2359296
constexpr size_t GRAM_HALFS = (size_t)NB * NP * NP;      // 5308416

__device__ __forceinline__ unsigned f2bf(float x) {
  unsigned u = __float_as_uint(x);
  return (u + 0x7FFFu + ((u >> 16) & 1u)) >> 16;   // RNE to bf16
}

// ---- kernel 1: pack x1/x2 even rows+cols -> K-major bf16 [b][p][c] ----
__global__ __launch_bounds__(256) void corr_pack(
    const float* __restrict__ x1, const float* __restrict__ x2,
    unsigned short* __restrict__ apk, unsigned short* __restrict__ bpk)
{
  const int h = blockIdx.x;    // downsampled row 0..23
  const int b = blockIdx.y;
  const int s = blockIdx.z;    // 0: x1->apk, 1: x2->bpk
  const int t = threadIdx.x;
  const float* src = (s ? x2 : x1) + (size_t)b * NC * HW + (size_t)(2 * h) * NW;
  unsigned short* dst = (s ? bpk : apk) + ((size_t)b * NP + h * 24) * NC;

  __shared__ unsigned short T[24][264];   // [w1][c], row stride 264 halfs (16B mult)

  float4 R[12];
  #pragma unroll
  for (int q = 0; q < 12; ++q) {         // items c(256) x w4(12)
    const int idx = t + q * 256;
    const int c = idx / 12, w4 = idx % 12;
    R[q] = *(const float4*)&src[(size_t)c * HW + 4 * w4];
  }
  #pragma unroll
  for (int q = 0; q < 12; ++q) {
    const int idx = t + q * 256;
    const int c = idx / 12, w4 = idx % 12;
    T[2 * w4][c]     = (unsigned short)f2bf(R[q].x);   // orig col 4w4   -> w1=2w4
    T[2 * w4 + 1][c] = (unsigned short)f2bf(R[q].z);   // orig col 4w4+2 -> w1=2w4+1
  }
  __syncthreads();
  #pragma unroll
  for (int q = 0; q < 3; ++q) {          // items p(24) x g(32 x 16B)
    const int idx = t + q * 256;
    const int p = idx >> 5, g = idx & 31;
    *(uint4*)&dst[(size_t)p * NC + g * 8] = *(const uint4*)&T[p][g * 8];
  }
}

// ---- kernel 2: banded 64x64 GEMM tiles, K=256, fp16 Gram output ----
__global__ __launch_bounds__(256) void corr_gemm(
    const unsigned short* __restrict__ apk, const unsigned short* __restrict__ bpk,
    __half* __restrict__ gram)
{
  static const signed char pairP[39] = {0,0,0, 1,1,1,1, 2,2,2,2,2, 3,3,3,3,3,
                                        4,4,4,4,4, 5,5,5,5,5, 6,6,6,6,6,
                                        7,7,7,7, 8,8,8};
  static const signed char pairQ[39] = {0,1,2, 0,1,2,3, 0,1,2,3,4, 1,2,3,4,5,
                                        2,3,4,5,6, 3,4,5,6,7, 4,5,6,7,8,
                                        5,6,7,8, 6,7,8};
  const int pr = blockIdx.x;             // 0..38
  const int b  = blockIdx.y;
  const int P = pairP[pr], Q = pairQ[pr];
  const int t = threadIdx.x;
  const int wv = t >> 6, ln15 = t & 15, lh = (t & 63) >> 4;

  __shared__ __align__(16) unsigned short At[64][128];   // 16 KB, T2-swizzled
  __shared__ __align__(16) unsigned short Bt[64][128];   // 16 KB

  const unsigned short* abase = apk + ((size_t)b * NP + P * 64) * NC;
  const unsigned short* bbase = bpk + ((size_t)b * NP + Q * 64) * NC;

  uint4 RA[4], RB[4];
  auto loadsg = [&](int kc) {            // items row(64) x g(16 x 16B) per operand
    #pragma unroll
    for (int q = 0; q < 4; ++q) {
      const int idx = t + q * 256;
      const int row = idx >> 4, g = idx & 15;
      const size_t off = (size_t)row * NC + kc * 128 + g * 8;
      RA[q] = *(const uint4*)(abase + off);
      RB[q] = *(const uint4*)(bbase + off);
    }
  };
  auto ldsw = [&]() {                    // store with gs = g ^ (row&7)
    #pragma unroll
    for (int q = 0; q < 4; ++q) {
      const int idx = t + q * 256;
      const int row = idx >> 4, g = idx & 15;
      const int gs = g ^ (row & 7);
      *(uint4*)&At[row][gs * 8] = RA[q];
      *(uint4*)&Bt[row][gs * 8] = RB[q];
    }
  };

  f32x4 acc[4];
  #pragma unroll
  for (int pt = 0; pt < 4; ++pt) acc[pt] = (f32x4){0.f, 0.f, 0.f, 0.f};

  const int qrow = wv * 16 + ln15;
  auto compute = [&]() {
    #pragma unroll
    for (int ks = 0; ks < 4; ++ks) {
      const int gr = ks * 4 + lh;        // k granule (k = gr*8..gr*8+7 of chunk)
      const short8 bf = *(const short8*)&Bt[qrow][(gr ^ (qrow & 7)) * 8];
      #pragma unroll
      for (int pt = 0; pt < 4; ++pt) {
        const int prow = pt * 16 + ln15;
        const short8 af = *(const short8*)&At[prow][(gr ^ (prow & 7)) * 8];
        acc[pt] = __builtin_amdgcn_mfma_f32_16x16x32_bf16(af, bf, acc[pt], 0, 0, 0);
      }
    }
  };

  loadsg(0); ldsw(); __syncthreads();
  loadsg(1);             // chunk-1 HBM/L2 latency hides under compute(0)
  compute(); __syncthreads();
  ldsw(); __syncthreads();
  compute();

  // D layout (m89-verified): col(q) = lane&15, row(p) = (lane>>4)*4 + reg
  __half* gb = gram + ((size_t)b * NP + P * 64) * NP + Q * 64;
  #pragma unroll
  for (int pt = 0; pt < 4; ++pt)
    #pragma unroll
    for (int r = 0; r < 4; ++r) {
      const int p = pt * 16 + lh * 4 + r;
      gb[(size_t)p * NP + wv * 16 + ln15] = __float2half(acc[pt][r]);
    }
}

// ---- kernel 3: band gather + boundary zeros + 1/256 ----
__global__ __launch_bounds__(256) void corr_gather(
    const __half* __restrict__ gram, float* __restrict__ out)
{
  const int h1 = blockIdx.x;   // 0..23
  const int b  = blockIdx.y;
  const int t  = threadIdx.x;
  __shared__ __half Gl[24][9][28];   // [w1][dy][x], padded rows (8B-aligned)

  const __half* gbase = gram + (size_t)b * NP * NP;
  uint2 R[6];
  #pragma unroll
  for (int q = 0; q < 6; ++q) {          // items w1(24) x dy(9) x f2(6 x 8B)
    const int idx = t + q * 256;
    if (idx < 1296) {
      const int f2 = idx % 6;
      const int dy = (idx / 6) % 9;
      const int w1 = idx / 54;
      const int y = h1 - 4 + dy;
      uint2 v = make_uint2(0u, 0u);
      if (y >= 0 && y < 24)
        v = *(const uint2*)(gbase + (size_t)(h1 * 24 + w1) * NP + 24 * y + f2 * 4);
      R[q] = v;
    }
  }
  #pragma unroll
  for (int q = 0; q < 6; ++q) {
    const int idx = t + q * 256;
    if (idx < 1296) {
      const int f2 = idx % 6;
      const int dy = (idx / 6) % 9;
      const int w1 = idx / 54;
      *(uint2*)&Gl[w1][dy][f2 * 4] = R[q];
    }
  }
  __syncthreads();

  float* obase = out + (size_t)b * NK * (H1 * W1) + h1 * 24;
  #pragma unroll
  for (int q = 0; q < 2; ++q) {          // items k(81) x w4(6)
    const int idx = t + q * 256;
    if (idx < 486) {
      const int w4 = idx % 6;
      const int k  = idx / 6;
      const int j = k / 9, i = k % 9;
      float v[4];
      #pragma unroll
      for (int w = 0; w < 4; ++w) {
        const int w1 = w4 * 4 + w;
        const int x = w1 + i - 4;
        v[w] = (x >= 0 && x < 24) ? __half2float(Gl[w1][j][x]) * (1.f / 256.f) : 0.f;
      }
      *(float4*)&obase[(size_t)k * (H1 * W1) + w4 * 4] =
          make_float4(v[0], v[1], v[2], v[3]);
    }
  }
}

// ---- fallback (ws too small): vector kernel, atomicAdd into out ----
__global__ __launch_bounds__(256, 4) void corr_atomic(
    const float* __restrict__ x1, const float* __restrict__ x2,
    float* __restrict__ out)
{
  const int t   = threadIdx.x;
  const int h1t = blockIdx.x;
  const int b   = blockIdx.y;
  const int cz  = blockIdx.z;     // 0..7, 32 ch each
  const int h1base = h1t * 4;
  __shared__ float s1m[16][4][24];
  __shared__ float s2m[16][12][36];
  const int h1l = t / 54, rr = t % 54, j = rr / 6, wg = rr % 6;
  const float* base1 = x1 + (size_t)(b * NC + cz * 32) * HW;
  const float* base2 = x2 + (size_t)(b * NC + cz * 32) * HW;
  float acc[9][4];
  #pragma unroll
  for (int i = 0; i < 9; ++i) { acc[i][0]=0.f; acc[i][1]=0.f; acc[i][2]=0.f; acc[i][3]=0.f; }
  for (int ch = 0; ch < 2; ++ch) {
    if (ch) __syncthreads();
    const float* p2 = base2 + (size_t)ch * 16 * HW;
    #pragma unroll
    for (int q = 0; q < 12; ++q) {
      const int idx = t + q * 256;
      const int xh = idx & 15, r = (idx >> 4) % 12, c = idx / 192;
      const int ys = h1base - 4 + r;
      float vx = 0.f, vz = 0.f;
      if (ys >= 0 && ys < H1 && xh >= 2 && xh <= 13) {
        const float4 v = *(const float4*)&p2[(size_t)c * HW + (size_t)(2 * ys) * NW + (4 * xh - 8)];
        vx = v.x; vz = v.z;
      }
      s2m[c][r][2 * xh] = vx; s2m[c][r][2 * xh + 1] = vz;
    }
    const float* p1 = base1 + (size_t)ch * 16 * HW;
    #pragma unroll
    for (int q = 0; q < 3; ++q) {
      const int idx = t + q * 256;
      const int xq = idx % 12, hh = (idx / 12) & 3, c = idx / 48;
      const float4 v = *(const float4*)&p1[(size_t)c * HW + (size_t)(2 * (h1base + hh)) * NW + 4 * xq];
      s1m[c][hh][2 * xq] = v.x; s1m[c][hh][2 * xq + 1] = v.z;
    }
    __syncthreads();
    if (t < 216) {
      #pragma unroll 4
      for (int c = 0; c < 16; ++c) {
        const float4 a4 = *(const float4*)&s1m[c][h1l][wg * 4];
        const float* xr = &s2m[c][h1l + j][wg * 4];
        const float4 b0 = *(const float4*)&xr[0];
        const float4 b1 = *(const float4*)&xr[4];
        const float4 b2 = *(const float4*)&xr[8];
        const float av[4]  = {a4.x, a4.y, a4.z, a4.w};
        const float xw[12] = {b0.x,b0.y,b0.z,b0.w,b1.x,b1.y,b1.z,b1.w,b2.x,b2.y,b2.z,b2.w};
        #pragma unroll
        for (int i = 0; i < 9; ++i)
          #pragma unroll
          for (int w = 0; w < 4; ++w)
            acc[i][w] = fmaf(av[w], xw[w + i], acc[i][w]);
      }
    }
  }
  if (t >= 216) return;
  const int h1 = h1base + h1l, w1 = wg * 4;
  #pragma unroll
  for (int i = 0; i < 9; ++i) {
    const int k = j * 9 + i;
    #pragma unroll
    for (int w = 0; w < 4; ++w)
      atomicAdd(&out[((size_t)(b * NK + k) * H1 + h1) * W1 + w1 + w],
                acc[i][w] * (1.f / 256.f));
  }
}

extern "C" void kernel_launch(void* const* d_in, const int* in_sizes, int n_in,
                              void* d_out, int out_size, void* d_ws, size_t ws_size,
                              hipStream_t stream) {
  const float* x1 = (const float*)d_in[0];
  const float* x2 = (const float*)d_in[1];
  float* out = (float*)d_out;

  const size_t need = (2 * APK_HALFS + GRAM_HALFS) * 2;   // ~20.05 MB
  if (ws_size >= need) {
    unsigned short* apk = (unsigned short*)d_ws;
    unsigned short* bpk = apk + APK_HALFS;
    __half* gram = (__half*)(bpk + APK_HALFS);
    corr_pack<<<dim3(24, NB, 2), 256, 0, stream>>>(x1, x2, apk, bpk);
    corr_gemm<<<dim3(39, NB), 256, 0, stream>>>(apk, bpk, gram);
    corr_gather<<<dim3(24, NB), 256, 0, stream>>>(gram, out);
  } else {
    hipMemsetAsync(d_out, 0, (size_t)OUTSZ * sizeof(float), stream);
    corr_atomic<<<dim3(6, NB, 8), 256, 0, stream>>>(x1, x2, out);
  }
}

// Round 13
// 27.007 us; speedup vs baseline: 1.3885x; 1.3885x over previous
//
#include <hip/hip_runtime.h>
#include <hip/hip_fp16.h>

// Correlation layer, specialized: s1=2, s2=1, d=4 -> integer even sampling,
// bilinear weights exactly 0 -> pure gather:
// out[b, j*9+i, h1, w1] = (1/256) * sum_c x1[b,c,2h1,2w1] * x2[b,c,2(h1+j-4),2(w1+i-4)]
// (zero when displaced downsampled position is outside the 24x24 grid)
//
// Best-known configuration (round 6: 26.8 us, reproduced round 11: 27.0 us):
// CSPLIT=8 x 32ch (two 16-ch LDS chunks, register-pipelined), 768 blocks x
// 256 thr, fp16 transposed partials (11.9 MB) + coalesced reduce kernel.

constexpr int NB = 16, NC = 256, NH = 48, NW = 48;
constexpr int H1 = 24, W1 = 24, NK = 81, HW = NH * NW;
constexpr int CSPLIT = 8, CPB = 32, CCH = 16;  // 8 blocks x 32ch, staged 16/chunk
constexpr int TH = 4;                           // h1 rows per block -> h1t 0..5
constexpr int NTILE = (H1 / TH) * NB;           // 96 spatial tiles
constexpr int NT = 216;                         // compute threads (4h x 9j x 6wg)
constexpr int PPT = 9 * NT;                     // 1944 Half4 per (tile,cz)
constexpr int OUTSZ = NB * NK * H1 * W1;        // 746496

struct alignas(8) Half4 { __half2 a, b; };

// MODE 0: fp16 transposed partials in ws + coalesced reduce kernel
// MODE 1: atomicAdd fallback if ws too small
template<int MODE>
__global__ __launch_bounds__(256, 4) void corr_main(
    const float* __restrict__ x1, const float* __restrict__ x2,
    void* __restrict__ dst)
{
  const int t   = threadIdx.x;
  const int h1t = blockIdx.x;   // 0..5
  const int b   = blockIdx.y;   // 0..15
  const int cz  = blockIdx.z;   // 0..7
  const int h1base = h1t * TH;

  __shared__ float s1[CCH][TH][24];   // 6 KB
  __shared__ float s2[CCH][12][36];   // 27.6 KB (32 data cols + pad)

  const int h1l = t / 54;             // compute decomposition: 216 active
  const int rr  = t % 54;
  const int j   = rr / 6;
  const int wg  = rr % 6;

  const float* base1 = x1 + (size_t)(b * NC + cz * CPB) * HW;
  const float* base2 = x2 + (size_t)(b * NC + cz * CPB) * HW;

  float4 R2[12], R1[3];               // staging registers, reused across chunks

  auto loads = [&](int chunk) {
    const float* p2 = base2 + (size_t)chunk * CCH * HW;
    #pragma unroll
    for (int q = 0; q < 12; ++q) {
      const int idx = t + q * 256;    // xh(16) r(12) c(16)
      const int xh = idx & 15;
      const int r  = (idx >> 4) % 12;
      const int c  = idx / 192;
      const int ys = h1base - 4 + r;
      R2[q] = make_float4(0.f, 0.f, 0.f, 0.f);
      if (ys >= 0 && ys < H1 && xh >= 2 && xh <= 13)
        R2[q] = *(const float4*)&p2[(size_t)c * HW + (size_t)(2 * ys) * NW + (4 * xh - 8)];
    }
    const float* p1 = base1 + (size_t)chunk * CCH * HW;
    #pragma unroll
    for (int q = 0; q < 3; ++q) {
      const int idx = t + q * 256;    // xq(12) hh(4) c(16)
      const int xq = idx % 12;
      const int hh = (idx / 12) & 3;
      const int c  = idx / 48;
      R1[q] = *(const float4*)&p1[(size_t)c * HW + (size_t)(2 * (h1base + hh)) * NW + 4 * xq];
    }
  };
  auto ldswrite = [&]() {             // keep .x,.z of each stride-2 float4
    #pragma unroll
    for (int q = 0; q < 12; ++q) {
      const int idx = t + q * 256;
      const int xh = idx & 15;
      const int r  = (idx >> 4) % 12;
      const int c  = idx / 192;
      s2[c][r][2 * xh]     = R2[q].x;
      s2[c][r][2 * xh + 1] = R2[q].z;
    }
    #pragma unroll
    for (int q = 0; q < 3; ++q) {
      const int idx = t + q * 256;
      const int xq = idx % 12;
      const int hh = (idx / 12) & 3;
      const int c  = idx / 48;
      s1[c][hh][2 * xq]     = R1[q].x;
      s1[c][hh][2 * xq + 1] = R1[q].z;
    }
  };

  float acc[9][4];
  #pragma unroll
  for (int i = 0; i < 9; ++i) { acc[i][0]=0.f; acc[i][1]=0.f; acc[i][2]=0.f; acc[i][3]=0.f; }

  auto compute = [&]() {
    if (t >= NT) return;
    #pragma unroll 4
    for (int c = 0; c < CCH; ++c) {
      const float4 a4 = *(const float4*)&s1[c][h1l][wg * 4];
      const float* xr = &s2[c][h1l + j][wg * 4];
      const float4 b0 = *(const float4*)&xr[0];
      const float4 b1 = *(const float4*)&xr[4];
      const float4 b2 = *(const float4*)&xr[8];
      const float av[4]  = {a4.x, a4.y, a4.z, a4.w};
      const float xw[12] = {b0.x, b0.y, b0.z, b0.w, b1.x, b1.y, b1.z, b1.w,
                            b2.x, b2.y, b2.z, b2.w};
      #pragma unroll
      for (int i = 0; i < 9; ++i)
        #pragma unroll
        for (int w = 0; w < 4; ++w)
          acc[i][w] = fmaf(av[w], xw[w + i], acc[i][w]);
    }
  };

  // pipelined 2-chunk schedule: chunk-1 loads issue before chunk-0 compute
  loads(0);
  ldswrite();
  __syncthreads();
  loads(1);          // HBM latency hides under compute below
  compute();
  __syncthreads();   // all chunk-0 readers done before overwrite
  ldswrite();
  __syncthreads();
  compute();

  if (MODE == 0) {
    if (t >= NT) return;
    // transposed fp16 partials: wave store = 512 B contiguous per i
    const int tile = h1t * NB + b;
    Half4* pb = (Half4*)dst + ((size_t)cz * NTILE + tile) * PPT;
    #pragma unroll
    for (int i = 0; i < 9; ++i) {
      Half4 h;
      h.a = __floats2half2_rn(acc[i][0], acc[i][1]);
      h.b = __floats2half2_rn(acc[i][2], acc[i][3]);
      pb[i * NT + t] = h;
    }
  } else {
    if (t >= NT) return;
    float* out = (float*)dst;
    const int h1 = h1base + h1l;
    const int w1 = wg * 4;
    #pragma unroll
    for (int i = 0; i < 9; ++i) {
      const int k = j * 9 + i;
      #pragma unroll
      for (int w = 0; w < 4; ++w)
        atomicAdd(&out[((size_t)(b * NK + k) * H1 + h1) * W1 + w1 + w],
                  acc[i][w] * (1.f / 256.f));
    }
  }
}

// Coalesced reduce: consecutive threads read consecutive Half4s per cz slice.
__global__ __launch_bounds__(256) void corr_reduce(const Half4* __restrict__ part,
                                                   float* __restrict__ out)
{
  const int n = blockIdx.x * 256 + threadIdx.x;   // 0 .. 186623
  if (n >= OUTSZ / 4) return;
  const int tile = n / PPT;          // h1t*16 + b
  const int rem  = n % PPT;          // i*216 + tp
  const int i    = rem / NT;
  const int tp   = rem % NT;

  float4 s = make_float4(0.f, 0.f, 0.f, 0.f);
  #pragma unroll
  for (int cz = 0; cz < CSPLIT; ++cz) {
    const Half4 v = part[((size_t)cz * NTILE + tile) * PPT + rem];
    const float2 lo = __half22float2(v.a);
    const float2 hi = __half22float2(v.b);
    s.x += lo.x; s.y += lo.y; s.z += hi.x; s.w += hi.y;
  }
  const float sc = 1.f / (float)NC;
  const int b   = tile % NB;
  const int h1t = tile / NB;
  const int h1l = tp / 54;
  const int r2  = tp % 54;
  const int j   = r2 / 6;
  const int wg  = r2 % 6;
  const int k   = j * 9 + i;
  const int h1  = h1t * TH + h1l;
  *(float4*)&out[(((size_t)b * NK + k) * H1 + h1) * W1 + wg * 4] =
      make_float4(s.x * sc, s.y * sc, s.z * sc, s.w * sc);
}

extern "C" void kernel_launch(void* const* d_in, const int* in_sizes, int n_in,
                              void* d_out, int out_size, void* d_ws, size_t ws_size,
                              hipStream_t stream) {
  const float* x1 = (const float*)d_in[0];
  const float* x2 = (const float*)d_in[1];
  float* out = (float*)d_out;

  const size_t need = (size_t)CSPLIT * NTILE * PPT * sizeof(Half4);  // ~11.9 MB
  const dim3 grid(H1 / TH, NB, CSPLIT);   // (6, 16, 8) = 768 blocks
  if (ws_size >= need) {
    corr_main<0><<<grid, 256, 0, stream>>>(x1, x2, d_ws);
    corr_reduce<<<(OUTSZ / 4 + 255) / 256, 256, 0, stream>>>((const Half4*)d_ws, out);
  } else {
    hipMemsetAsync(d_out, 0, (size_t)OUTSZ * sizeof(float), stream);
    corr_main<1><<<grid, 256, 0, stream>>>(x1, x2, d_out);
  }
}